// Round 4
// baseline (37.377 us; speedup 1.0000x reference)
//
#include <hip/hip_runtime.h>
#include <math.h>

#define NYX 192
#define NNODE 193
#define L_NODES (NNODE*NNODE)     /* 37249 */
#define NPAIR 11
#define NB 2
#define NCH 12
#define NGRP (NPAIR*NB)           /* 22 reduction groups         */
#define NBLK 146                  /* ceil(37249/256) node blocks */

/* ws layout: float4 partials[NGRP*NBLK] at offset 0 (51392 B) */

__global__ __launch_bounds__(256) void sdice_node(const float* __restrict__ pred,
                                                  const float* __restrict__ labels,
                                                  const float* __restrict__ area,
                                                  float4* __restrict__ partials)
{
    const int pair = blockIdx.z;
    const int b    = blockIdx.y;
    const int l    = blockIdx.x * 256 + threadIdx.x;

    float num = 0.f, den = 0.f, bces = 0.f, cnt = 0.f;

    if (l < L_NODES) {
        const int j  = l / NNODE;
        const int ix = l - j * NNODE;

        float sig[8], bcv[8];
        int byte = 0;
        #pragma unroll
        for (int c = 0; c < 2; ++c) {
            const size_t base = (size_t)(b * NCH + pair + c) * (NYX * NYX);
            #pragma unroll
            for (int ky = 0; ky < 2; ++ky) {
                const int y = j - 1 + ky;
                #pragma unroll
                for (int kx = 0; kx < 2; ++kx) {
                    const int x = ix - 1 + kx;
                    const int k = c * 4 + ky * 2 + kx;
                    const bool inb = ((unsigned)y < NYX) && ((unsigned)x < NYX);
                    float pv = 0.f, lv = 0.f;
                    if (inb) {
                        const size_t off = base + (size_t)y * NYX + x;
                        pv = pred[off];
                        lv = labels[off];
                    }
                    byte |= ((int)lv) << k;
                    /* pad AFTER sigmoid -> up = literal 0 at borders */
                    sig[k] = inb ? (1.0f / (1.0f + expf(-pv))) : 0.0f;
                    /* for !inb: pv=lv=0 -> bcv = log1p(exp(0)) = ln2, matching ref's padded bce */
                    bcv[k] = fmaxf(pv, 0.f) - pv * lv + log1pf(expf(-fabsf(pv)));
                }
            }
        }

        float d2 = 0.f;
        #pragma unroll
        for (int k = 0; k < 8; ++k) {
            const float d = sig[k] - (float)((byte >> k) & 1);
            d2 += d * d;
        }
        const float w_lab = 1.0f - sqrtf(d2) * (1.0f / 16.0f);
        const float la = area[byte];
        num = w_lab * la;
        den = la;
        if (byte == 0 || byte == 255) {
            cnt = 1.f;
            bces = ((bcv[0] + bcv[1]) + (bcv[2] + bcv[3])) + ((bcv[4] + bcv[5]) + (bcv[6] + bcv[7]));
        }
    }

    /* wave shuffle reduce, then cross-wave via LDS */
    #pragma unroll
    for (int off = 32; off > 0; off >>= 1) {
        num  += __shfl_down(num, off);
        den  += __shfl_down(den, off);
        bces += __shfl_down(bces, off);
        cnt  += __shfl_down(cnt, off);
    }
    __shared__ float sred[4][4];
    const int lane = threadIdx.x & 63;
    const int wid  = threadIdx.x >> 6;
    if (lane == 0) { sred[wid][0] = num; sred[wid][1] = den; sred[wid][2] = bces; sred[wid][3] = cnt; }
    __syncthreads();
    if (threadIdx.x == 0) {
        float n = 0, d = 0, bc = 0, ct = 0;
        #pragma unroll
        for (int w = 0; w < 4; ++w) { n += sred[w][0]; d += sred[w][1]; bc += sred[w][2]; ct += sred[w][3]; }
        partials[(size_t)(pair * NB + b) * NBLK + blockIdx.x] = make_float4(n, d, bc, ct);
    }
}

__global__ __launch_bounds__(256) void sdice_final(const float4* __restrict__ partials,
                                                   const float* __restrict__ area,
                                                   float* __restrict__ out)
{
    __shared__ float gs[NGRP][4];
    const int wid  = threadIdx.x >> 6;
    const int lane = threadIdx.x & 63;

    for (int g = wid; g < NGRP; g += 4) {
        float n = 0.f, d = 0.f, bc = 0.f, ct = 0.f;
        for (int i = lane; i < NBLK; i += 64) {
            const float4 v = partials[(size_t)g * NBLK + i];
            n += v.x; d += v.y; bc += v.z; ct += v.w;
        }
        #pragma unroll
        for (int off = 32; off > 0; off >>= 1) {
            n  += __shfl_down(n, off);
            d  += __shfl_down(d, off);
            bc += __shfl_down(bc, off);
            ct += __shfl_down(ct, off);
        }
        if (lane == 0) { gs[g][0] = n; gs[g][1] = d; gs[g][2] = bc; gs[g][3] = ct; }
    }
    __syncthreads();
    if (threadIdx.x == 0) {
        const float a1 = area[1];   /* pred_byte == 1 everywhere (strict '>' in fori_loop) */
        float dice_sum = 0.f, vol_sum = 0.f;
        for (int b = 0; b < NB; ++b) {
            float numb = 0.f, denb = 0.f, volb = 0.f;
            for (int p = 0; p < NPAIR; ++p) {
                const int g = p * NB + b;
                numb += 2.0f * gs[g][0];
                denb += gs[g][1] + (float)L_NODES * a1;
                volb += gs[g][2] / (8.0f * gs[g][3]);
            }
            dice_sum += 1.0f - (numb + 0.001f) / (denb + 0.001f);
            vol_sum  += volb;
        }
        out[0] = dice_sum / (float)NB + vol_sum / (float)NB;
    }
}

extern "C" void kernel_launch(void* const* d_in, const int* in_sizes, int n_in,
                              void* d_out, int out_size, void* d_ws, size_t ws_size,
                              hipStream_t stream) {
    const float* pred   = (const float*)d_in[0];
    const float* labels = (const float*)d_in[1];
    const float* area   = (const float*)d_in[2];
    float* out = (float*)d_out;
    float4* part = (float4*)d_ws;

    dim3 grid(NBLK, NB, NPAIR);
    sdice_node<<<grid, dim3(256), 0, stream>>>(pred, labels, area, part);
    sdice_final<<<1, 256, 0, stream>>>(part, area, out);
}

// Round 5
// 19.403 us; speedup vs baseline: 1.9264x; 1.9264x over previous
//
#include <hip/hip_runtime.h>
#include <math.h>

#define NYX 192
#define NNODE 193
#define L_NODES (NNODE*NNODE)     /* 37249 */
#define NPAIR 11
#define NB 2
#define NCH 12
#define NGRP (NPAIR*NB)           /* 22 reduction groups */
#define NBLK 49                   /* row-blocks: ceil(193 rows / 4 rows-per-block) */
#define LN2f 0.69314718055994530942f

/* ws: float4 partials[NGRP*NBLK] (22*49*16 = 17248 B) */

__global__ __launch_bounds__(256) void sdice_node(const float* __restrict__ pred,
                                                  const float* __restrict__ labels,
                                                  const float* __restrict__ area,
                                                  float4* __restrict__ partials)
{
    const int pair = blockIdx.z;
    const int b    = blockIdx.y;
    const int lane = threadIdx.x & 63;   /* one wave == one node row; lanes 0..47 active */
    const int wrow = threadIdx.x >> 6;
    const int j    = blockIdx.x * 4 + wrow;   /* node row 0..195 (guard j<193) */
    const int t    = lane;                    /* x-group: nodes 4t..4t+3 */

    __shared__ float areas[256];
    __shared__ float sred[4][4];
    areas[threadIdx.x] = area[threadIdx.x];
    __syncthreads();

    float num = 0.f, den = 0.f, bces = 0.f, cnt = 0.f;
    const bool act = (j < NNODE) && (t < 48);

    if (act) {
        /* windows over x = 4t-1 .. 4t+4 for each (c,ky)=cr:
           sig6/bcv6 idx 0..5 <-> x = 4t-1 .. 4t+4 ; w5 bit i <-> label bit at x = 4t-1+i */
        float sig6[4][6], bcv6[4][6];
        unsigned w5[4];

        const int  y0 = (j >= 1) ? (j - 1) : 0;          /* clamped rows, loads always valid */
        const int  y1 = (j <= NYX - 1) ? j : (NYX - 1);
        const bool m0 = (j >= 1);
        const bool m1 = (j <= NYX - 1);
        const int  xo = t * 4;

        #pragma unroll
        for (int c = 0; c < 2; ++c) {
            const size_t base = (size_t)(b * NCH + pair + c) * (NYX * NYX);
            #pragma unroll
            for (int r = 0; r < 2; ++r) {
                const int  cr = c * 2 + r;
                const int  yy = r ? y1 : y0;
                const bool mm = r ? m1 : m0;
                const float4 p4 = *reinterpret_cast<const float4*>(pred   + base + (size_t)yy * NYX + xo);
                const float4 l4 = *reinterpret_cast<const float4*>(labels + base + (size_t)yy * NYX + xo);
                const float pe[4] = {p4.x, p4.y, p4.z, p4.w};
                const float le[4] = {l4.x, l4.y, l4.z, l4.w};
                unsigned bits = 0;
                #pragma unroll
                for (int e = 0; e < 4; ++e) {
                    const float pv = mm ? pe[e] : 0.f;   /* row-OOB -> padded zeros */
                    const float lv = mm ? le[e] : 0.f;
                    bits |= ((unsigned)lv) << e;
                    const float s = __builtin_amdgcn_rcpf(1.f + __expf(-pv));
                    sig6[cr][e + 1] = mm ? s : 0.f;      /* pad AFTER sigmoid -> 0 */
                    /* pv=lv=0 at pad -> ln2, matching reference's padded bce */
                    bcv6[cr][e + 1] = fmaxf(pv, 0.f) - pv * lv + __logf(1.f + __expf(-fabsf(pv)));
                }
                w5[cr] = bits << 1;
                sig6[cr][5] = 0.f;      /* x = 4t+4 slot, only used by node 192 (x OOB) */
                bcv6[cr][5] = LN2f;
            }
        }

        /* x = 4t-1 halo from lane-1 (wave is row-aligned; lane 0 is the real x=0 border) */
        #pragma unroll
        for (int cr = 0; cr < 4; ++cr) {
            const float    sw = __shfl_up(sig6[cr][4], 1);
            const float    bw = __shfl_up(bcv6[cr][4], 1);
            const unsigned ww = (unsigned)__shfl_up((int)w5[cr], 1);
            sig6[cr][0] = (t == 0) ? 0.f  : sw;
            bcv6[cr][0] = (t == 0) ? LN2f : bw;
            w5[cr]     |= (t == 0) ? 0u   : ((ww >> 4) & 1u);
        }

        /* nodes ix = 4t+i ; i=4 (ix=192) only on lane 47 */
        #pragma unroll
        for (int i = 0; i < 5; ++i) {
            if (i < 4 || t == 47) {
                unsigned byte = 0;
                float d2 = 0.f, bsum = 0.f;
                #pragma unroll
                for (int cr = 0; cr < 4; ++cr) {
                    const unsigned bp = (w5[cr] >> i) & 1u;        /* kx=0 */
                    const unsigned bc = (w5[cr] >> (i + 1)) & 1u;  /* kx=1 */
                    byte |= (bp << (2 * cr)) | (bc << (2 * cr + 1));
                    const float dp = sig6[cr][i]     - (float)bp;
                    const float dc = sig6[cr][i + 1] - (float)bc;
                    d2   += dp * dp + dc * dc;
                    bsum += bcv6[cr][i] + bcv6[cr][i + 1];
                }
                const float w  = 1.f - sqrtf(d2) * (1.f / 16.f);
                const float la = areas[byte];
                num += w * la;
                den += la;
                const bool msk = (byte == 0u) || (byte == 255u);
                cnt  += msk ? 1.f : 0.f;
                bces += msk ? bsum : 0.f;
            }
        }
    }

    /* wave shuffle reduce + cross-wave LDS + non-atomic block partial */
    #pragma unroll
    for (int off = 32; off > 0; off >>= 1) {
        num  += __shfl_down(num, off);
        den  += __shfl_down(den, off);
        bces += __shfl_down(bces, off);
        cnt  += __shfl_down(cnt, off);
    }
    if (lane == 0) { sred[wrow][0] = num; sred[wrow][1] = den; sred[wrow][2] = bces; sred[wrow][3] = cnt; }
    __syncthreads();
    if (threadIdx.x == 0) {
        float n = 0, d = 0, bc = 0, ct = 0;
        #pragma unroll
        for (int w = 0; w < 4; ++w) { n += sred[w][0]; d += sred[w][1]; bc += sred[w][2]; ct += sred[w][3]; }
        partials[(size_t)(pair * NB + b) * NBLK + blockIdx.x] = make_float4(n, d, bc, ct);
    }
}

__global__ __launch_bounds__(256) void sdice_final(const float4* __restrict__ partials,
                                                   const float* __restrict__ area,
                                                   float* __restrict__ out)
{
    __shared__ float gs[NGRP][4];
    const int wid  = threadIdx.x >> 6;
    const int lane = threadIdx.x & 63;

    for (int g = wid; g < NGRP; g += 4) {
        float n = 0.f, d = 0.f, bc = 0.f, ct = 0.f;
        for (int i = lane; i < NBLK; i += 64) {
            const float4 v = partials[(size_t)g * NBLK + i];
            n += v.x; d += v.y; bc += v.z; ct += v.w;
        }
        #pragma unroll
        for (int off = 32; off > 0; off >>= 1) {
            n  += __shfl_down(n, off);
            d  += __shfl_down(d, off);
            bc += __shfl_down(bc, off);
            ct += __shfl_down(ct, off);
        }
        if (lane == 0) { gs[g][0] = n; gs[g][1] = d; gs[g][2] = bc; gs[g][3] = ct; }
    }
    __syncthreads();
    if (threadIdx.x == 0) {
        const float a1 = area[1];   /* pred_byte == 1 everywhere (strict '>' in fori_loop) */
        float dice_sum = 0.f, vol_sum = 0.f;
        for (int b = 0; b < NB; ++b) {
            float numb = 0.f, denb = 0.f, volb = 0.f;
            for (int p = 0; p < NPAIR; ++p) {
                const int g = p * NB + b;
                numb += 2.0f * gs[g][0];
                denb += gs[g][1] + (float)L_NODES * a1;
                volb += gs[g][2] / (8.0f * gs[g][3]);
            }
            dice_sum += 1.0f - (numb + 0.001f) / (denb + 0.001f);
            vol_sum  += volb;
        }
        out[0] = dice_sum / (float)NB + vol_sum / (float)NB;
    }
}

extern "C" void kernel_launch(void* const* d_in, const int* in_sizes, int n_in,
                              void* d_out, int out_size, void* d_ws, size_t ws_size,
                              hipStream_t stream) {
    const float* pred   = (const float*)d_in[0];
    const float* labels = (const float*)d_in[1];
    const float* area   = (const float*)d_in[2];
    float* out = (float*)d_out;
    float4* part = (float4*)d_ws;

    dim3 grid(NBLK, NB, NPAIR);
    sdice_node<<<grid, dim3(256), 0, stream>>>(pred, labels, area, part);
    sdice_final<<<1, 256, 0, stream>>>(part, area, out);
}